// Round 14
// baseline (781.720 us; speedup 1.0000x reference)
//
#include <hip/hip_runtime.h>
#include <stdint.h>

#define NNODES 100000
#define NEDGES 600000
#define NGRAPH 256
#define KCH 5
#define F1 16
#define O1 64
#define F2 128
#define O2 256
#define FT1 (KCH * F1) /* 80  */
#define FT2 (KCH * F2) /* 640 */
#define KSTEPS 20      /* 640/32 */
#define KS1 3          /* ceil(80/32) for layer-1 MFMA GEMM (K padded to 96) */
#define LROW 40        /* LDS row stride in ushorts: 80 B -> 16B-aligned rows */
#define LD8 512        /* fp8 shadow leading dim (4 slices x 128) */

typedef unsigned short ushort_t;
typedef __attribute__((ext_vector_type(8))) short bf16x8;
typedef __attribute__((ext_vector_type(4))) float f32x4;
typedef __attribute__((ext_vector_type(2))) float f32x2;

__device__ __forceinline__ float bflo(unsigned int u) {
    union { unsigned int u; float f; } v; v.u = u << 16; return v.f;
}
__device__ __forceinline__ float bfhi(unsigned int u) {
    union { unsigned int u; float f; } v; v.u = u & 0xFFFF0000u; return v.f;
}
__device__ __forceinline__ unsigned int f2bf(float f) {
    union { float f; unsigned int u; } v; v.f = f;
    return (v.u + 0x7FFFu + ((v.u >> 16) & 1u)) >> 16;  // RNE
}
__device__ __forceinline__ unsigned int pack2(float lo, float hi) {
    return (f2bf(hi) << 16) | f2bf(lo);
}

// -------------------- CSR build --------------------

__global__ void k_count(const int* __restrict__ src, const int* __restrict__ dst,
                        int* __restrict__ cntDst, int* __restrict__ cntSrc, int E) {
    int e = blockIdx.x * 256 + threadIdx.x;
    if (e < E) {
        atomicAdd(&cntDst[dst[e]], 1);
        atomicAdd(&cntSrc[src[e]], 1);
    }
}

__global__ void k_dinv(const int* __restrict__ cntDst, const int* __restrict__ cntSrc,
                       float* __restrict__ dinvF, float* __restrict__ dinvR, int n) {
    int i = blockIdx.x * 256 + threadIdx.x;
    if (i < n) {
        int cs = cntSrc[i], cd = cntDst[i];
        dinvF[i] = cs > 0 ? rsqrtf((float)cs) : 0.f;  // deg over src -> fwd norm
        dinvR[i] = cd > 0 ? rsqrtf((float)cd) : 0.f;  // deg over dst -> rev norm
    }
}

// exclusive scan, 512 elems/block
__global__ void k_scan1(const int* __restrict__ in, int* __restrict__ out,
                        int* __restrict__ blksum, int n) {
    __shared__ int a[512];
    __shared__ int s[256];
    int t = threadIdx.x;
    int base = blockIdx.x * 512;
    a[t]       = (base + t < n)       ? in[base + t]       : 0;
    a[t + 256] = (base + t + 256 < n) ? in[base + t + 256] : 0;
    __syncthreads();
    s[t] = a[2 * t] + a[2 * t + 1];
    __syncthreads();
    for (int off = 1; off < 256; off <<= 1) {
        int v = (t >= off) ? s[t - off] : 0;
        __syncthreads();
        s[t] += v;
        __syncthreads();
    }
    int ep = (t > 0) ? s[t - 1] : 0;  // exclusive over pairs
    if (base + 2 * t < n)     out[base + 2 * t]     = ep;
    if (base + 2 * t + 1 < n) out[base + 2 * t + 1] = ep + a[2 * t];
    if (t == 255) blksum[blockIdx.x] = s[255];
}

__global__ void k_scan2(int* __restrict__ blksum, int nb) {
    __shared__ int s[256];
    int t = threadIdx.x;
    s[t] = (t < nb) ? blksum[t] : 0;
    __syncthreads();
    for (int off = 1; off < 256; off <<= 1) {
        int v = (t >= off) ? s[t - off] : 0;
        __syncthreads();
        s[t] += v;
        __syncthreads();
    }
    if (t < nb) blksum[t] = (t > 0) ? s[t - 1] : 0;
}

__global__ void k_scan3(int* __restrict__ out, const int* __restrict__ blksum, int n) {
    int i = blockIdx.x * 512 + threadIdx.x;
    int add = blksum[blockIdx.x];
    if (i < n) out[i] += add;
    if (i + 256 < n) out[i + 256] += add;
}

__global__ void k_tail(int* __restrict__ off_f, int* __restrict__ off_r, int n, int E) {
    if (threadIdx.x == 0) { off_f[n] = E; off_r[n] = E; }
}

// edge record = {nbr, weight} packed in one int2 -> single 8B random store
__global__ void k_scatter(const int* __restrict__ src, const int* __restrict__ dst,
                          const float* __restrict__ dinvF, const float* __restrict__ dinvR,
                          int* __restrict__ curF, int* __restrict__ curR,
                          int2* __restrict__ edF, int2* __restrict__ edR, int E) {
    int e = blockIdx.x * 256 + threadIdx.x;
    if (e < E) {
        int s = src[e], d = dst[e];
        int p = atomicAdd(&curF[d], 1);
        float wf = -dinvF[s] * dinvF[d];
        edF[p] = make_int2(s, __float_as_int(wf));
        int q = atomicAdd(&curR[s], 1);
        float wr = -dinvR[s] * dinvR[d];
        edR[q] = make_int2(d, __float_as_int(wr));
    }
}

__global__ void k_gstart(const int* __restrict__ batch, int* __restrict__ gstart, int n) {
    int g = blockIdx.x * 64 + threadIdx.x;
    if (g > NGRAPH) return;
    if (g == NGRAPH) { gstart[g] = n; return; }
    int lo = 0, hi = n;
    while (lo < hi) {
        int mid = (lo + hi) >> 1;
        if (batch[mid] < g) lo = mid + 1; else hi = mid;
    }
    gstart[g] = lo;
}

// -------------------- compute --------------------

__global__ void k_copyx(const float* __restrict__ x, float* __restrict__ Tx, int n) {
    int tid = blockIdx.x * 256 + threadIdx.x;
    int r = tid >> 2, c = tid & 3;
    if (r < n)
        *(float4*)(Tx + (size_t)r * FT1 + c * 4) =
            *(const float4*)(x + (size_t)r * 16 + c * 4);
}

// fp32 SpMM (layer 1, F=16): 4 lanes/row, float4/lane; edge loop unrolled x4
__global__ void k_spmm_f32(const float* __restrict__ Hin, float* __restrict__ Hout,
                           const float* __restrict__ Tx0,
                           const int* __restrict__ off, const int2* __restrict__ ed,
                           int n) {
    int tid = blockIdx.x * 256 + threadIdx.x;
    int r = tid >> 2, c = tid & 3;
    if (r >= n) return;
    int j0 = off[r], j1 = off[r + 1];
    float4 s = {0.f, 0.f, 0.f, 0.f};
    int j = j0;
    for (; j + 4 <= j1; j += 4) {
        int2 e0 = ed[j], e1 = ed[j + 1], e2 = ed[j + 2], e3 = ed[j + 3];
        float wa = __int_as_float(e0.y), wb = __int_as_float(e1.y);
        float wc = __int_as_float(e2.y), wd = __int_as_float(e3.y);
        const float4 h0 = *(const float4*)(Hin + (size_t)e0.x * FT1 + c * 4);
        const float4 h1 = *(const float4*)(Hin + (size_t)e1.x * FT1 + c * 4);
        const float4 h2 = *(const float4*)(Hin + (size_t)e2.x * FT1 + c * 4);
        const float4 h3 = *(const float4*)(Hin + (size_t)e3.x * FT1 + c * 4);
        s.x += wa * h0.x; s.y += wa * h0.y; s.z += wa * h0.z; s.w += wa * h0.w;
        s.x += wb * h1.x; s.y += wb * h1.y; s.z += wb * h1.z; s.w += wb * h1.w;
        s.x += wc * h2.x; s.y += wc * h2.y; s.z += wc * h2.z; s.w += wc * h2.w;
        s.x += wd * h3.x; s.y += wd * h3.y; s.z += wd * h3.z; s.w += wd * h3.w;
    }
    for (; j < j1; ++j) {
        int2 e = ed[j];
        float w2 = __int_as_float(e.y);
        const float4 h = *(const float4*)(Hin + (size_t)e.x * FT1 + c * 4);
        s.x += w2 * h.x; s.y += w2 * h.y; s.z += w2 * h.z; s.w += w2 * h.w;
    }
    float4 o;
    if (Tx0) {
        const float4 t0 = *(const float4*)(Tx0 + (size_t)r * FT1 + c * 4);
        o.x = 2.f * s.x - t0.x; o.y = 2.f * s.y - t0.y;
        o.z = 2.f * s.z - t0.z; o.w = 2.f * s.w - t0.w;
    } else {
        o = s;
    }
    *(float4*)(Hout + (size_t)r * FT1 + c * 4) = o;
}

// bf16 slice -> fp8 shadow slice 0 (2 feats per thread)
__global__ void k_cvt0(const ushort_t* __restrict__ Hbf, uint8_t* __restrict__ H8, int n) {
    int tid = blockIdx.x * 256 + threadIdx.x;
    int r = tid >> 6, c = tid & 63;
    if (r >= n) return;
    unsigned int u = *(const unsigned int*)(Hbf + (size_t)r * FT2 + c * 2);
    int p = __builtin_amdgcn_cvt_pk_fp8_f32(bflo(u), bfhi(u), 0, false);
    *(ushort_t*)(H8 + (size_t)r * LD8 + c * 2) = (ushort_t)p;
}

// fp8-gather SpMM (layer 2, F=128): one wave per row, scalar edge stream,
// clamped 8-slot edge block; gathers 2 fp8/lane (128 B/edge, half of bf16).
// Output: bf16 (combine + GEMM operand) and optional fp8 shadow for next gather.
__global__ void k_spmm_bf(const uint8_t* __restrict__ Hin8, ushort_t* __restrict__ Hout,
                          uint8_t* __restrict__ Hout8,
                          const ushort_t* __restrict__ Tx0,
                          const int* __restrict__ off, const int2* __restrict__ ed,
                          int n) {
    int r = blockIdx.x * 4 + (threadIdx.x >> 6);
    r = __builtin_amdgcn_readfirstlane(r);   // wave-uniform -> scalar edge loads
    int c = threadIdx.x & 63;
    if (r >= n) return;
    int j0 = __builtin_amdgcn_readfirstlane(off[r]);
    int j1 = __builtin_amdgcn_readfirstlane(off[r + 1]);
    float s0 = 0.f, s1 = 0.f;
    for (int j = j0; j < j1; j += 8) {
        float w[8];
        int h[8];
#pragma unroll
        for (int sl = 0; sl < 8; ++sl) {
            int jj = j + sl;
            int jc = jj < j1 ? jj : j1 - 1;
            int2 e = ed[jc];
            w[sl] = (jj < j1) ? __int_as_float(e.y) : 0.f;
            h[sl] = *(const ushort_t*)(Hin8 + (size_t)e.x * LD8 + c * 2);
        }
#pragma unroll
        for (int sl = 0; sl < 8; ++sl) {
            f32x2 f = __builtin_amdgcn_cvt_pk_f32_fp8(h[sl], false);
            s0 = fmaf(f.x, w[sl], s0);
            s1 = fmaf(f.y, w[sl], s1);
        }
    }
    if (Tx0) {
        unsigned int t0 = *(const unsigned int*)(Tx0 + (size_t)r * FT2 + c * 2);
        s0 = 2.f * s0 - bflo(t0);
        s1 = 2.f * s1 - bfhi(t0);
    }
    *(unsigned int*)(Hout + (size_t)r * FT2 + c * 2) = pack2(s0, s1);
    if (Hout8) {
        int p = __builtin_amdgcn_cvt_pk_fp8_f32(s0, s1, 0, false);
        *(ushort_t*)(Hout8 + (size_t)r * LD8 + c * 2) = (ushort_t)p;
    }
}

// pack W [80,64] fp32 -> bf16 MFMA B-frags, K zero-padded 80 -> 96 (KS1 ksteps)
__global__ void k_packW1(const float* __restrict__ W, ushort_t* __restrict__ Bp) {
    int tid = blockIdx.x * 256 + threadIdx.x;  // 4*KS1*64 = 768 threads
    if (tid >= 4 * KS1 * 64) return;
    int lane = tid & 63;
    int ks = (tid >> 6) % KS1;
    int nt = tid / (64 * KS1);
    int k0 = ks * 32 + (lane >> 4) * 8;
    int ncol = nt * 16 + (lane & 15);
    float v[8];
#pragma unroll
    for (int j = 0; j < 8; ++j) {
        int k = k0 + j;
        v[j] = (k < FT1) ? W[(size_t)k * O1 + ncol] : 0.f;
    }
    uint4 o;
    o.x = pack2(v[0], v[1]); o.y = pack2(v[2], v[3]);
    o.z = pack2(v[4], v[5]); o.w = pack2(v[6], v[7]);
    *(uint4*)(Bp + (size_t)tid * 8) = o;
}

// layer-1 MFMA GEMM: A fp32 [n,80] (k-padded reads to 96) x Bp bf16 -> bf16 out
// slice (ld=640), bias+relu. Block = 4 waves; wave w: rows blk*64+w*16..+16.
__global__ __launch_bounds__(256) void k_gemm1_mfma(
    const float* __restrict__ A, const ushort_t* __restrict__ Bp,
    const float* __restrict__ bias, ushort_t* __restrict__ out, int n) {
    int lane = threadIdx.x & 63;
    int wvi = threadIdx.x >> 6;
    int mrow = lane & 15;
    int quad = lane >> 4;
    int m0w = blockIdx.x * 64 + wvi * 16;
    int row = m0w + mrow;
    int rowc = row < n ? row : n - 1;  // clamp loads; stores masked below
    const float* Ar = A + (size_t)rowc * FT1 + quad * 8;

    f32x4 acc[4] = {};
#pragma unroll
    for (int ks = 0; ks < KS1; ++ks) {
        float4 a0 = *(const float4*)(Ar + ks * 32);
        float4 a1 = *(const float4*)(Ar + ks * 32 + 4);
        union { bf16x8 v; unsigned int u[4]; } ua;
        ua.u[0] = pack2(a0.x, a0.y);
        ua.u[1] = pack2(a0.z, a0.w);
        ua.u[2] = pack2(a1.x, a1.y);
        ua.u[3] = pack2(a1.z, a1.w);
#pragma unroll
        for (int nf = 0; nf < 4; ++nf) {
            bf16x8 bfr = *(const bf16x8*)(Bp + ((size_t)(nf * KS1 + ks) * 64 + lane) * 8);
            acc[nf] = __builtin_amdgcn_mfma_f32_16x16x32_bf16(ua.v, bfr, acc[nf], 0, 0, 0);
        }
    }
    // C/D layout: col = nf*16 + (lane&15), row = m0w + quad*4 + reg
#pragma unroll
    for (int nf = 0; nf < 4; ++nf) {
        float bb = bias[nf * 16 + mrow];
#pragma unroll
        for (int reg = 0; reg < 4; ++reg) {
            int orow = m0w + quad * 4 + reg;
            if (orow < n)
                out[(size_t)orow * FT2 + nf * 16 + mrow] =
                    (ushort_t)f2bf(fmaxf(acc[nf][reg] + bb, 0.f));
        }
    }
}

// pack W [640,256] fp32 row-major -> bf16 MFMA B-fragment layout
__global__ void k_packW(const float* __restrict__ W, ushort_t* __restrict__ Bp) {
    int tid = blockIdx.x * 256 + threadIdx.x;  // 16*KSTEPS*64 = 20480 threads
    if (tid >= 16 * KSTEPS * 64) return;
    int lane = tid & 63;
    int ks = (tid >> 6) % KSTEPS;
    int nt = tid / (64 * KSTEPS);
    int k0 = ks * 32 + (lane >> 4) * 8;
    int ncol = nt * 16 + (lane & 15);
    float v[8];
#pragma unroll
    for (int j = 0; j < 8; ++j) v[j] = W[(size_t)(k0 + j) * O2 + ncol];
    uint4 o;
    o.x = pack2(v[0], v[1]); o.y = pack2(v[2], v[3]);
    o.z = pack2(v[4], v[5]); o.w = pack2(v[6], v[7]);
    *(uint4*)(Bp + (size_t)tid * 8) = o;
}

// layer-2 MFMA GEMM, double-buffered LDS (16B-aligned 80 B rows) with
// one-iteration-ahead register prefetch.
__global__ __launch_bounds__(256) void k_gemm2_mfma(
    const ushort_t* __restrict__ A, const ushort_t* __restrict__ Bp,
    const float* __restrict__ bias, float* __restrict__ pooled, int colofs,
    const int* __restrict__ batch, int n) {
    __shared__ ushort_t lds[2][64 * LROW];  // 2 x 5120 B

    int lane = threadIdx.x & 63;
    int wv = threadIdx.x >> 6;
    int m0 = blockIdx.x * 64;
    int mrow = lane & 15;
    int quad = lane >> 4;
    int srow = threadIdx.x >> 2;  // staging row 0..63
    int sc = threadIdx.x & 3;     // staging 16B chunk 0..3

    const ushort_t* Ag = A + (size_t)(m0 + srow) * FT2 + sc * 8;
    const ushort_t* Bbase = Bp + ((size_t)(wv * 4) * KSTEPS * 64 + lane) * 8;
    int sidx = srow * LROW + sc * 8;

    f32x4 acc[4][4] = {};  // [mfrag][nfrag]

    // prologue: stage 0 -> buf0; issue load for stage 1 (lands next iteration)
    uint4 nxt;
    {
        uint4 c0 = *(const uint4*)(Ag);
        *(uint4*)&lds[0][sidx] = c0;
        nxt = *(const uint4*)(Ag + 32);
    }

    for (int ks = 0; ks < KSTEPS; ++ks) {
        __syncthreads();
        // write stage ks+1 (loaded one iteration ago) into the other buffer
        if (ks + 1 < KSTEPS)
            *(uint4*)&lds[(ks + 1) & 1][sidx] = nxt;
        // issue load for stage ks+2 (consumed next iteration)
        if (ks + 2 < KSTEPS)
            nxt = *(const uint4*)(Ag + (ks + 2) * 32);
        bf16x8 af[4], bfr[4];
        const ushort_t* lbuf = &lds[ks & 1][0];
#pragma unroll
        for (int mf = 0; mf < 4; ++mf)
            af[mf] = *(const bf16x8*)(lbuf + (mf * 16 + mrow) * LROW + quad * 8);
#pragma unroll
        for (int nf = 0; nf < 4; ++nf)
            bfr[nf] = *(const bf16x8*)(Bbase + ((size_t)nf * KSTEPS + ks) * 64 * 8);
#pragma unroll
        for (int mf = 0; mf < 4; ++mf)
#pragma unroll
            for (int nf = 0; nf < 4; ++nf)
                acc[mf][nf] = __builtin_amdgcn_mfma_f32_16x16x32_bf16(
                    af[mf], bfr[nf], acc[mf][nf], 0, 0, 0);
    }

    // epilogue: C/D layout col=lane&15, row=quad*4+reg; pool into pooled[g*512+colofs+col]
    float bcol[4];
#pragma unroll
    for (int nf = 0; nf < 4; ++nf) bcol[nf] = bias[wv * 64 + nf * 16 + mrow];

#pragma unroll
    for (int mf = 0; mf < 4; ++mf) {
        int t0 = m0 + mf * 16;
        if (t0 >= n) break;
        int te = (t0 + 15 < n) ? t0 + 15 : n - 1;
        int r0 = t0 + quad * 4;
        if (batch[t0] == batch[te]) {
            // whole 16-row tile in one graph: cross-quad reduce, 1 atomic / (nf, col)
            int g = batch[t0];
#pragma unroll
            for (int nf = 0; nf < 4; ++nf) {
                float s = 0.f;
#pragma unroll
                for (int reg = 0; reg < 4; ++reg) {
                    float v = fmaxf(acc[mf][nf][reg] + bcol[nf], 0.f);
                    if (r0 + reg < n) s += v;
                }
                s += __shfl_xor(s, 16, 64);
                s += __shfl_xor(s, 32, 64);
                if (quad == 0)
                    atomicAdd(pooled + (size_t)g * 512 + colofs + wv * 64 + nf * 16 + mrow, s);
            }
        } else {
            // boundary tile: per-lane run merge over 4 consecutive rows
            int gb[4];
#pragma unroll
            for (int reg = 0; reg < 4; ++reg)
                gb[reg] = batch[(r0 + reg < n) ? r0 + reg : n - 1];
#pragma unroll
            for (int nf = 0; nf < 4; ++nf) {
                int col = colofs + wv * 64 + nf * 16 + mrow;
                float run = 0.f;
                int g = gb[0];
                bool any = false;
#pragma unroll
                for (int reg = 0; reg < 4; ++reg) {
                    int row = r0 + reg;
                    if (row >= n) break;
                    float v = fmaxf(acc[mf][nf][reg] + bcol[nf], 0.f);
                    if (gb[reg] != g) {
                        atomicAdd(pooled + (size_t)g * 512 + col, run);
                        run = 0.f;
                        g = gb[reg];
                    }
                    run += v;
                    any = true;
                }
                if (any) atomicAdd(pooled + (size_t)g * 512 + col, run);
            }
        }
    }
}

__global__ void k_logits(const float* __restrict__ pooled, const int* __restrict__ gstart,
                         const float* __restrict__ fcw, const float* __restrict__ fcb,
                         float* __restrict__ out) {
    int g = threadIdx.x;
    int cnt = gstart[g + 1] - gstart[g];
    float inv = 1.f / (float)(cnt > 1 ? cnt : 1);
    float lg[4];
#pragma unroll
    for (int o = 0; o < 4; ++o) lg[o] = fcb[o];
    for (int f = 0; f < 512; ++f) {
        float p = pooled[g * 512 + f] * inv;
#pragma unroll
        for (int o = 0; o < 4; ++o) lg[o] = fmaf(p, fcw[f * 4 + o], lg[o]);
    }
    float m = fmaxf(fmaxf(lg[0], lg[1]), fmaxf(lg[2], lg[3]));
    float s = 0.f;
#pragma unroll
    for (int o = 0; o < 4; ++o) s += expf(lg[o] - m);
    float l = logf(s);
#pragma unroll
    for (int o = 0; o < 4; ++o) out[g * 4 + o] = lg[o] - m - l;
}

// -------------------- launch --------------------

extern "C" void kernel_launch(void* const* d_in, const int* in_sizes, int n_in,
                              void* d_out, int out_size, void* d_ws, size_t ws_size,
                              hipStream_t stream) {
    const float* x   = (const float*)d_in[0];
    const int* ei    = (const int*)d_in[1];
    const int* batch = (const int*)d_in[2];
    const float* W11 = (const float*)d_in[3];
    const float* b11 = (const float*)d_in[4];
    const float* W12 = (const float*)d_in[5];
    const float* b12 = (const float*)d_in[6];
    const float* W21 = (const float*)d_in[7];
    const float* b21 = (const float*)d_in[8];
    const float* W22 = (const float*)d_in[9];
    const float* b22 = (const float*)d_in[10];
    const float* fcw = (const float*)d_in[11];
    const float* fcb = (const float*)d_in[12];
    float* out = (float*)d_out;

    const int N = in_sizes[0] / F1;
    const int E = in_sizes[1] / 2;
    const int* src = ei;
    const int* dst = ei + E;

    char* w = (char*)d_ws;
    size_t pos = 0;
    auto alloc = [&](size_t bytes) -> void* {
        void* p = w + pos;
        pos += (bytes + 255) & ~(size_t)255;
        return p;
    };
    int* cur_f   = (int*)alloc((size_t)N * 4);
    int* cur_r   = (int*)alloc((size_t)N * 4);
    int* off_f   = (int*)alloc((size_t)(N + 1) * 4);
    int* off_r   = (int*)alloc((size_t)(N + 1) * 4);
    float* dinvF = (float*)alloc((size_t)N * 4);
    float* dinvR = (float*)alloc((size_t)N * 4);
    int2* ed_f   = (int2*)alloc((size_t)E * 8);
    int2* ed_r   = (int2*)alloc((size_t)E * 8);
    int* blks_f  = (int*)alloc(1024);
    int* blks_r  = (int*)alloc(1024);
    int* gstart  = (int*)alloc((NGRAPH + 1) * 4);
    float* pooled = (float*)alloc((size_t)NGRAPH * 512 * 4);
    ushort_t* BpF = (ushort_t*)alloc((size_t)FT2 * O2 * 2);      // 320 KB packed W21
    ushort_t* BpR = (ushort_t*)alloc((size_t)FT2 * O2 * 2);      // 320 KB packed W22
    ushort_t* Bp1F = (ushort_t*)alloc((size_t)4 * KS1 * 64 * 8 * 2);  // 12 KB packed W11
    ushort_t* Bp1R = (ushort_t*)alloc((size_t)4 * KS1 * 64 * 8 * 2);  // 12 KB packed W12
    // union region: TxAll1 (fp32 layer-1 Cheb, dies after gemm1-rev) aliases
    // Tx8 (fp8 gather shadow, born after gemm1-rev via k_cvt0) — disjoint lifetimes.
    size_t tx1_bytes = ((size_t)N * FT1 + 256) * 4;   // 32.1 MB
    size_t tx8_bytes = (size_t)N * LD8 + 256;         // 51.2 MB
    char* uni = (char*)alloc(tx1_bytes > tx8_bytes ? tx1_bytes : tx8_bytes);
    float* TxAll1 = (float*)uni;
    uint8_t* Tx8  = (uint8_t*)uni;
    ushort_t* TxAll2 = (ushort_t*)alloc((size_t)(N + 64) * FT2 * 2);  // 128 MB bf16 + pad
    // total ~193 MB

    (void)hipMemsetAsync(cur_f, 0, (size_t)N * 4, stream);
    (void)hipMemsetAsync(cur_r, 0, (size_t)N * 4, stream);
    (void)hipMemsetAsync(pooled, 0, (size_t)NGRAPH * 512 * 4, stream);

    int gE = (E + 255) / 256, gN = (N + 255) / 256;
    k_count<<<gE, 256, 0, stream>>>(src, dst, cur_f, cur_r, E);
    k_dinv<<<gN, 256, 0, stream>>>(cur_f, cur_r, dinvF, dinvR, N);

    int NB = (N + 511) / 512;
    k_scan1<<<NB, 256, 0, stream>>>(cur_f, off_f, blks_f, N);
    k_scan1<<<NB, 256, 0, stream>>>(cur_r, off_r, blks_r, N);
    k_scan2<<<1, 256, 0, stream>>>(blks_f, NB);
    k_scan2<<<1, 256, 0, stream>>>(blks_r, NB);
    k_scan3<<<NB, 256, 0, stream>>>(off_f, blks_f, N);
    k_scan3<<<NB, 256, 0, stream>>>(off_r, blks_r, N);
    k_tail<<<1, 64, 0, stream>>>(off_f, off_r, N, E);
    (void)hipMemcpyAsync(cur_f, off_f, (size_t)N * 4, hipMemcpyDeviceToDevice, stream);
    (void)hipMemcpyAsync(cur_r, off_r, (size_t)N * 4, hipMemcpyDeviceToDevice, stream);
    k_scatter<<<gE, 256, 0, stream>>>(src, dst, dinvF, dinvR, cur_f, cur_r,
                                      ed_f, ed_r, E);
    k_gstart<<<5, 64, 0, stream>>>(batch, gstart, N);
    k_packW<<<80, 256, 0, stream>>>(W21, BpF);
    k_packW<<<80, 256, 0, stream>>>(W22, BpR);
    k_packW1<<<3, 256, 0, stream>>>(W11, Bp1F);
    k_packW1<<<3, 256, 0, stream>>>(W12, Bp1R);

    // ---------------- layer 1 (fp32 Tx, F=16) ----------------
    k_copyx<<<(N * 4 + 255) / 256, 256, 0, stream>>>(x, TxAll1, N);
    int gs1 = (N * 4 + 255) / 256;
    int gg1 = (N + 63) / 64;
    auto C1 = [&](int k) { return TxAll1 + k * F1; };
    // fwd
    k_spmm_f32<<<gs1, 256, 0, stream>>>(C1(0), C1(1), nullptr, off_f, ed_f, N);
    k_spmm_f32<<<gs1, 256, 0, stream>>>(C1(1), C1(2), C1(0), off_f, ed_f, N);
    k_spmm_f32<<<gs1, 256, 0, stream>>>(C1(2), C1(3), C1(1), off_f, ed_f, N);
    k_spmm_f32<<<gs1, 256, 0, stream>>>(C1(3), C1(4), C1(2), off_f, ed_f, N);
    k_gemm1_mfma<<<gg1, 256, 0, stream>>>(TxAll1, Bp1F, b11, TxAll2, N);
    // rev (overwrites C1(1..4); C1(0)=x preserved)
    k_spmm_f32<<<gs1, 256, 0, stream>>>(C1(0), C1(1), nullptr, off_r, ed_r, N);
    k_spmm_f32<<<gs1, 256, 0, stream>>>(C1(1), C1(2), C1(0), off_r, ed_r, N);
    k_spmm_f32<<<gs1, 256, 0, stream>>>(C1(2), C1(3), C1(1), off_r, ed_r, N);
    k_spmm_f32<<<gs1, 256, 0, stream>>>(C1(3), C1(4), C1(2), off_r, ed_r, N);
    k_gemm1_mfma<<<gg1, 256, 0, stream>>>(TxAll1, Bp1R, b12, TxAll2 + O1, N);

    // ---------------- layer 2 (bf16 Tx + fp8 gather shadow, F=128) ----------------
    // TxAll1 is dead now; Tx8 aliases its memory.
    k_cvt0<<<(N * 64 + 255) / 256, 256, 0, stream>>>(TxAll2, Tx8, N);
    int gs2 = (N + 3) / 4;
    auto C2 = [&](int k) { return TxAll2 + k * F2; };
    auto S8 = [&](int k) { return Tx8 + (size_t)k * F2; };
    int gg = (N + 63) / 64;
    // fwd
    k_spmm_bf<<<gs2, 256, 0, stream>>>(S8(0), C2(1), S8(1), nullptr, off_f, ed_f, N);
    k_spmm_bf<<<gs2, 256, 0, stream>>>(S8(1), C2(2), S8(2), C2(0), off_f, ed_f, N);
    k_spmm_bf<<<gs2, 256, 0, stream>>>(S8(2), C2(3), S8(3), C2(1), off_f, ed_f, N);
    k_spmm_bf<<<gs2, 256, 0, stream>>>(S8(3), C2(4), nullptr, C2(2), off_f, ed_f, N);
    k_gemm2_mfma<<<gg, 256, 0, stream>>>(TxAll2, BpF, b21, pooled, 0, batch, N);
    // rev (overwrites S8(1..3); S8(0)=H preserved)
    k_spmm_bf<<<gs2, 256, 0, stream>>>(S8(0), C2(1), S8(1), nullptr, off_r, ed_r, N);
    k_spmm_bf<<<gs2, 256, 0, stream>>>(S8(1), C2(2), S8(2), C2(0), off_r, ed_r, N);
    k_spmm_bf<<<gs2, 256, 0, stream>>>(S8(2), C2(3), S8(3), C2(1), off_r, ed_r, N);
    k_spmm_bf<<<gs2, 256, 0, stream>>>(S8(3), C2(4), nullptr, C2(2), off_r, ed_r, N);
    k_gemm2_mfma<<<gg, 256, 0, stream>>>(TxAll2, BpR, b22, pooled, 256, batch, N);

    k_logits<<<1, 256, 0, stream>>>(pooled, gstart, fcw, fcb, out);
}

// Round 15
// 762.270 us; speedup vs baseline: 1.0255x; 1.0255x over previous
//
#include <hip/hip_runtime.h>
#include <stdint.h>

#define NNODES 100000
#define NEDGES 600000
#define NGRAPH 256
#define KCH 5
#define F1 16
#define O1 64
#define F2 128
#define O2 256
#define FT1 (KCH * F1) /* 80  */
#define FT2 (KCH * F2) /* 640 */
#define KSTEPS 20      /* 640/32 */
#define KS1 3          /* ceil(80/32) for layer-1 MFMA GEMM (K padded to 96) */
#define LROW 40        /* LDS row stride in ushorts: 80 B -> 16B-aligned rows */

typedef unsigned short ushort_t;
typedef __attribute__((ext_vector_type(8))) short bf16x8;
typedef __attribute__((ext_vector_type(4))) float f32x4;

__device__ __forceinline__ float bflo(unsigned int u) {
    union { unsigned int u; float f; } v; v.u = u << 16; return v.f;
}
__device__ __forceinline__ float bfhi(unsigned int u) {
    union { unsigned int u; float f; } v; v.u = u & 0xFFFF0000u; return v.f;
}
__device__ __forceinline__ unsigned int f2bf(float f) {
    union { float f; unsigned int u; } v; v.f = f;
    return (v.u + 0x7FFFu + ((v.u >> 16) & 1u)) >> 16;  // RNE
}
__device__ __forceinline__ unsigned int pack2(float lo, float hi) {
    return (f2bf(hi) << 16) | f2bf(lo);
}

// -------------------- CSR build --------------------

__global__ void k_count(const int* __restrict__ src, const int* __restrict__ dst,
                        int* __restrict__ cntDst, int* __restrict__ cntSrc, int E) {
    int e = blockIdx.x * 256 + threadIdx.x;
    if (e < E) {
        atomicAdd(&cntDst[dst[e]], 1);
        atomicAdd(&cntSrc[src[e]], 1);
    }
}

__global__ void k_dinv(const int* __restrict__ cntDst, const int* __restrict__ cntSrc,
                       float* __restrict__ dinvF, float* __restrict__ dinvR, int n) {
    int i = blockIdx.x * 256 + threadIdx.x;
    if (i < n) {
        int cs = cntSrc[i], cd = cntDst[i];
        dinvF[i] = cs > 0 ? rsqrtf((float)cs) : 0.f;  // deg over src -> fwd norm
        dinvR[i] = cd > 0 ? rsqrtf((float)cd) : 0.f;  // deg over dst -> rev norm
    }
}

// exclusive scan, 512 elems/block
__global__ void k_scan1(const int* __restrict__ in, int* __restrict__ out,
                        int* __restrict__ blksum, int n) {
    __shared__ int a[512];
    __shared__ int s[256];
    int t = threadIdx.x;
    int base = blockIdx.x * 512;
    a[t]       = (base + t < n)       ? in[base + t]       : 0;
    a[t + 256] = (base + t + 256 < n) ? in[base + t + 256] : 0;
    __syncthreads();
    s[t] = a[2 * t] + a[2 * t + 1];
    __syncthreads();
    for (int off = 1; off < 256; off <<= 1) {
        int v = (t >= off) ? s[t - off] : 0;
        __syncthreads();
        s[t] += v;
        __syncthreads();
    }
    int ep = (t > 0) ? s[t - 1] : 0;  // exclusive over pairs
    if (base + 2 * t < n)     out[base + 2 * t]     = ep;
    if (base + 2 * t + 1 < n) out[base + 2 * t + 1] = ep + a[2 * t];
    if (t == 255) blksum[blockIdx.x] = s[255];
}

__global__ void k_scan2(int* __restrict__ blksum, int nb) {
    __shared__ int s[256];
    int t = threadIdx.x;
    s[t] = (t < nb) ? blksum[t] : 0;
    __syncthreads();
    for (int off = 1; off < 256; off <<= 1) {
        int v = (t >= off) ? s[t - off] : 0;
        __syncthreads();
        s[t] += v;
        __syncthreads();
    }
    if (t < nb) blksum[t] = (t > 0) ? s[t - 1] : 0;
}

__global__ void k_scan3(int* __restrict__ out, const int* __restrict__ blksum, int n) {
    int i = blockIdx.x * 512 + threadIdx.x;
    int add = blksum[blockIdx.x];
    if (i < n) out[i] += add;
    if (i + 256 < n) out[i + 256] += add;
}

__global__ void k_tail(int* __restrict__ off_f, int* __restrict__ off_r, int n, int E) {
    if (threadIdx.x == 0) { off_f[n] = E; off_r[n] = E; }
}

// edge record = {nbr, weight} packed in one int2 -> single 8B random store
__global__ void k_scatter(const int* __restrict__ src, const int* __restrict__ dst,
                          const float* __restrict__ dinvF, const float* __restrict__ dinvR,
                          int* __restrict__ curF, int* __restrict__ curR,
                          int2* __restrict__ edF, int2* __restrict__ edR, int E) {
    int e = blockIdx.x * 256 + threadIdx.x;
    if (e < E) {
        int s = src[e], d = dst[e];
        int p = atomicAdd(&curF[d], 1);
        float wf = -dinvF[s] * dinvF[d];
        edF[p] = make_int2(s, __float_as_int(wf));
        int q = atomicAdd(&curR[s], 1);
        float wr = -dinvR[s] * dinvR[d];
        edR[q] = make_int2(d, __float_as_int(wr));
    }
}

__global__ void k_gstart(const int* __restrict__ batch, int* __restrict__ gstart, int n) {
    int g = blockIdx.x * 64 + threadIdx.x;
    if (g > NGRAPH) return;
    if (g == NGRAPH) { gstart[g] = n; return; }
    int lo = 0, hi = n;
    while (lo < hi) {
        int mid = (lo + hi) >> 1;
        if (batch[mid] < g) lo = mid + 1; else hi = mid;
    }
    gstart[g] = lo;
}

// -------------------- compute --------------------

__global__ void k_copyx(const float* __restrict__ x, float* __restrict__ Tx, int n) {
    int tid = blockIdx.x * 256 + threadIdx.x;
    int r = tid >> 2, c = tid & 3;
    if (r < n)
        *(float4*)(Tx + (size_t)r * FT1 + c * 4) =
            *(const float4*)(x + (size_t)r * 16 + c * 4);
}

// fp32 SpMM (layer 1, F=16): 4 lanes/row, float4/lane; edge loop unrolled x4
__global__ void k_spmm_f32(const float* __restrict__ Hin, float* __restrict__ Hout,
                           const float* __restrict__ Tx0,
                           const int* __restrict__ off, const int2* __restrict__ ed,
                           int n) {
    int tid = blockIdx.x * 256 + threadIdx.x;
    int r = tid >> 2, c = tid & 3;
    if (r >= n) return;
    int j0 = off[r], j1 = off[r + 1];
    float4 s = {0.f, 0.f, 0.f, 0.f};
    int j = j0;
    for (; j + 4 <= j1; j += 4) {
        int2 e0 = ed[j], e1 = ed[j + 1], e2 = ed[j + 2], e3 = ed[j + 3];
        float wa = __int_as_float(e0.y), wb = __int_as_float(e1.y);
        float wc = __int_as_float(e2.y), wd = __int_as_float(e3.y);
        const float4 h0 = *(const float4*)(Hin + (size_t)e0.x * FT1 + c * 4);
        const float4 h1 = *(const float4*)(Hin + (size_t)e1.x * FT1 + c * 4);
        const float4 h2 = *(const float4*)(Hin + (size_t)e2.x * FT1 + c * 4);
        const float4 h3 = *(const float4*)(Hin + (size_t)e3.x * FT1 + c * 4);
        s.x += wa * h0.x; s.y += wa * h0.y; s.z += wa * h0.z; s.w += wa * h0.w;
        s.x += wb * h1.x; s.y += wb * h1.y; s.z += wb * h1.z; s.w += wb * h1.w;
        s.x += wc * h2.x; s.y += wc * h2.y; s.z += wc * h2.z; s.w += wc * h2.w;
        s.x += wd * h3.x; s.y += wd * h3.y; s.z += wd * h3.z; s.w += wd * h3.w;
    }
    for (; j < j1; ++j) {
        int2 e = ed[j];
        float w2 = __int_as_float(e.y);
        const float4 h = *(const float4*)(Hin + (size_t)e.x * FT1 + c * 4);
        s.x += w2 * h.x; s.y += w2 * h.y; s.z += w2 * h.z; s.w += w2 * h.w;
    }
    float4 o;
    if (Tx0) {
        const float4 t0 = *(const float4*)(Tx0 + (size_t)r * FT1 + c * 4);
        o.x = 2.f * s.x - t0.x; o.y = 2.f * s.y - t0.y;
        o.z = 2.f * s.z - t0.z; o.w = 2.f * s.w - t0.w;
    } else {
        o = s;
    }
    *(float4*)(Hout + (size_t)r * FT1 + c * 4) = o;
}

// bf16 SpMM (layer 2, F=128): one wave per row, scalar edge stream; clamped
// 8-slot edge block -> all gathers of a row issued back-to-back (1 latency/row),
// OOB slots clamp to last edge with weight 0 (dup address, L1-cheap).
__global__ void k_spmm_bf(const ushort_t* __restrict__ Hin, ushort_t* __restrict__ Hout,
                          const ushort_t* __restrict__ Tx0,
                          const int* __restrict__ off, const int2* __restrict__ ed,
                          int n) {
    int r = blockIdx.x * 4 + (threadIdx.x >> 6);
    r = __builtin_amdgcn_readfirstlane(r);   // wave-uniform -> scalar edge loads
    int c = threadIdx.x & 63;
    if (r >= n) return;
    int j0 = __builtin_amdgcn_readfirstlane(off[r]);
    int j1 = __builtin_amdgcn_readfirstlane(off[r + 1]);
    float s0 = 0.f, s1 = 0.f;
    for (int j = j0; j < j1; j += 8) {
        float w[8];
        unsigned int h[8];
#pragma unroll
        for (int sl = 0; sl < 8; ++sl) {
            int jj = j + sl;
            int jc = jj < j1 ? jj : j1 - 1;
            int2 e = ed[jc];
            w[sl] = (jj < j1) ? __int_as_float(e.y) : 0.f;
            h[sl] = *(const unsigned int*)(Hin + (size_t)e.x * FT2 + c * 2);
        }
#pragma unroll
        for (int sl = 0; sl < 8; ++sl) {
            s0 = fmaf(bflo(h[sl]), w[sl], s0);
            s1 = fmaf(bfhi(h[sl]), w[sl], s1);
        }
    }
    if (Tx0) {
        unsigned int t0 = *(const unsigned int*)(Tx0 + (size_t)r * FT2 + c * 2);
        s0 = 2.f * s0 - bflo(t0);
        s1 = 2.f * s1 - bfhi(t0);
    }
    *(unsigned int*)(Hout + (size_t)r * FT2 + c * 2) = pack2(s0, s1);
}

// pack W [80,64] fp32 -> bf16 MFMA B-frags, K zero-padded 80 -> 96 (KS1 ksteps)
__global__ void k_packW1(const float* __restrict__ W, ushort_t* __restrict__ Bp) {
    int tid = blockIdx.x * 256 + threadIdx.x;  // 4*KS1*64 = 768 threads
    if (tid >= 4 * KS1 * 64) return;
    int lane = tid & 63;
    int ks = (tid >> 6) % KS1;
    int nt = tid / (64 * KS1);
    int k0 = ks * 32 + (lane >> 4) * 8;
    int ncol = nt * 16 + (lane & 15);
    float v[8];
#pragma unroll
    for (int j = 0; j < 8; ++j) {
        int k = k0 + j;
        v[j] = (k < FT1) ? W[(size_t)k * O1 + ncol] : 0.f;
    }
    uint4 o;
    o.x = pack2(v[0], v[1]); o.y = pack2(v[2], v[3]);
    o.z = pack2(v[4], v[5]); o.w = pack2(v[6], v[7]);
    *(uint4*)(Bp + (size_t)tid * 8) = o;
}

// layer-1 MFMA GEMM: A fp32 [n,80] (k-padded reads to 96) x Bp bf16 -> bf16 out
// slice (ld=640), bias+relu. Block = 4 waves; wave w: rows blk*64+w*16..+16.
__global__ __launch_bounds__(256) void k_gemm1_mfma(
    const float* __restrict__ A, const ushort_t* __restrict__ Bp,
    const float* __restrict__ bias, ushort_t* __restrict__ out, int n) {
    int lane = threadIdx.x & 63;
    int wvi = threadIdx.x >> 6;
    int mrow = lane & 15;
    int quad = lane >> 4;
    int m0w = blockIdx.x * 64 + wvi * 16;
    int row = m0w + mrow;
    int rowc = row < n ? row : n - 1;  // clamp loads; stores masked below
    const float* Ar = A + (size_t)rowc * FT1 + quad * 8;

    f32x4 acc[4] = {};
#pragma unroll
    for (int ks = 0; ks < KS1; ++ks) {
        float4 a0 = *(const float4*)(Ar + ks * 32);
        float4 a1 = *(const float4*)(Ar + ks * 32 + 4);
        union { bf16x8 v; unsigned int u[4]; } ua;
        ua.u[0] = pack2(a0.x, a0.y);
        ua.u[1] = pack2(a0.z, a0.w);
        ua.u[2] = pack2(a1.x, a1.y);
        ua.u[3] = pack2(a1.z, a1.w);
#pragma unroll
        for (int nf = 0; nf < 4; ++nf) {
            bf16x8 bfr = *(const bf16x8*)(Bp + ((size_t)(nf * KS1 + ks) * 64 + lane) * 8);
            acc[nf] = __builtin_amdgcn_mfma_f32_16x16x32_bf16(ua.v, bfr, acc[nf], 0, 0, 0);
        }
    }
    // C/D layout: col = nf*16 + (lane&15), row = m0w + quad*4 + reg
#pragma unroll
    for (int nf = 0; nf < 4; ++nf) {
        float bb = bias[nf * 16 + mrow];
#pragma unroll
        for (int reg = 0; reg < 4; ++reg) {
            int orow = m0w + quad * 4 + reg;
            if (orow < n)
                out[(size_t)orow * FT2 + nf * 16 + mrow] =
                    (ushort_t)f2bf(fmaxf(acc[nf][reg] + bb, 0.f));
        }
    }
}

// pack W [640,256] fp32 row-major -> bf16 MFMA B-fragment layout
__global__ void k_packW(const float* __restrict__ W, ushort_t* __restrict__ Bp) {
    int tid = blockIdx.x * 256 + threadIdx.x;  // 16*KSTEPS*64 = 20480 threads
    if (tid >= 16 * KSTEPS * 64) return;
    int lane = tid & 63;
    int ks = (tid >> 6) % KSTEPS;
    int nt = tid / (64 * KSTEPS);
    int k0 = ks * 32 + (lane >> 4) * 8;
    int ncol = nt * 16 + (lane & 15);
    float v[8];
#pragma unroll
    for (int j = 0; j < 8; ++j) v[j] = W[(size_t)(k0 + j) * O2 + ncol];
    uint4 o;
    o.x = pack2(v[0], v[1]); o.y = pack2(v[2], v[3]);
    o.z = pack2(v[4], v[5]); o.w = pack2(v[6], v[7]);
    *(uint4*)(Bp + (size_t)tid * 8) = o;
}

// layer-2 MFMA GEMM, double-buffered LDS (16B-aligned 80 B rows) with
// one-iteration-ahead register prefetch.
__global__ __launch_bounds__(256) void k_gemm2_mfma(
    const ushort_t* __restrict__ A, const ushort_t* __restrict__ Bp,
    const float* __restrict__ bias, float* __restrict__ pooled, int colofs,
    const int* __restrict__ batch, int n) {
    __shared__ ushort_t lds[2][64 * LROW];  // 2 x 5120 B

    int lane = threadIdx.x & 63;
    int wv = threadIdx.x >> 6;
    int m0 = blockIdx.x * 64;
    int mrow = lane & 15;
    int quad = lane >> 4;
    int srow = threadIdx.x >> 2;  // staging row 0..63
    int sc = threadIdx.x & 3;     // staging 16B chunk 0..3

    const ushort_t* Ag = A + (size_t)(m0 + srow) * FT2 + sc * 8;
    const ushort_t* Bbase = Bp + ((size_t)(wv * 4) * KSTEPS * 64 + lane) * 8;
    int sidx = srow * LROW + sc * 8;

    f32x4 acc[4][4] = {};  // [mfrag][nfrag]

    // prologue: stage 0 -> buf0; issue load for stage 1 (lands next iteration)
    uint4 nxt;
    {
        uint4 c0 = *(const uint4*)(Ag);
        *(uint4*)&lds[0][sidx] = c0;
        nxt = *(const uint4*)(Ag + 32);
    }

    for (int ks = 0; ks < KSTEPS; ++ks) {
        __syncthreads();
        // write stage ks+1 (loaded one iteration ago) into the other buffer
        if (ks + 1 < KSTEPS)
            *(uint4*)&lds[(ks + 1) & 1][sidx] = nxt;
        // issue load for stage ks+2 (consumed next iteration)
        if (ks + 2 < KSTEPS)
            nxt = *(const uint4*)(Ag + (ks + 2) * 32);
        bf16x8 af[4], bfr[4];
        const ushort_t* lbuf = &lds[ks & 1][0];
#pragma unroll
        for (int mf = 0; mf < 4; ++mf)
            af[mf] = *(const bf16x8*)(lbuf + (mf * 16 + mrow) * LROW + quad * 8);
#pragma unroll
        for (int nf = 0; nf < 4; ++nf)
            bfr[nf] = *(const bf16x8*)(Bbase + ((size_t)nf * KSTEPS + ks) * 64 * 8);
#pragma unroll
        for (int mf = 0; mf < 4; ++mf)
#pragma unroll
            for (int nf = 0; nf < 4; ++nf)
                acc[mf][nf] = __builtin_amdgcn_mfma_f32_16x16x32_bf16(
                    af[mf], bfr[nf], acc[mf][nf], 0, 0, 0);
    }

    // epilogue: C/D layout col=lane&15, row=quad*4+reg; pool into pooled[g*512+colofs+col]
    float bcol[4];
#pragma unroll
    for (int nf = 0; nf < 4; ++nf) bcol[nf] = bias[wv * 64 + nf * 16 + mrow];

#pragma unroll
    for (int mf = 0; mf < 4; ++mf) {
        int t0 = m0 + mf * 16;
        if (t0 >= n) break;
        int te = (t0 + 15 < n) ? t0 + 15 : n - 1;
        int r0 = t0 + quad * 4;
        if (batch[t0] == batch[te]) {
            // whole 16-row tile in one graph: cross-quad reduce, 1 atomic / (nf, col)
            int g = batch[t0];
#pragma unroll
            for (int nf = 0; nf < 4; ++nf) {
                float s = 0.f;
#pragma unroll
                for (int reg = 0; reg < 4; ++reg) {
                    float v = fmaxf(acc[mf][nf][reg] + bcol[nf], 0.f);
                    if (r0 + reg < n) s += v;
                }
                s += __shfl_xor(s, 16, 64);
                s += __shfl_xor(s, 32, 64);
                if (quad == 0)
                    atomicAdd(pooled + (size_t)g * 512 + colofs + wv * 64 + nf * 16 + mrow, s);
            }
        } else {
            // boundary tile: per-lane run merge over 4 consecutive rows
            int gb[4];
#pragma unroll
            for (int reg = 0; reg < 4; ++reg)
                gb[reg] = batch[(r0 + reg < n) ? r0 + reg : n - 1];
#pragma unroll
            for (int nf = 0; nf < 4; ++nf) {
                int col = colofs + wv * 64 + nf * 16 + mrow;
                float run = 0.f;
                int g = gb[0];
                bool any = false;
#pragma unroll
                for (int reg = 0; reg < 4; ++reg) {
                    int row = r0 + reg;
                    if (row >= n) break;
                    float v = fmaxf(acc[mf][nf][reg] + bcol[nf], 0.f);
                    if (gb[reg] != g) {
                        atomicAdd(pooled + (size_t)g * 512 + col, run);
                        run = 0.f;
                        g = gb[reg];
                    }
                    run += v;
                    any = true;
                }
                if (any) atomicAdd(pooled + (size_t)g * 512 + col, run);
            }
        }
    }
}

__global__ void k_logits(const float* __restrict__ pooled, const int* __restrict__ gstart,
                         const float* __restrict__ fcw, const float* __restrict__ fcb,
                         float* __restrict__ out) {
    int g = threadIdx.x;
    int cnt = gstart[g + 1] - gstart[g];
    float inv = 1.f / (float)(cnt > 1 ? cnt : 1);
    float lg[4];
#pragma unroll
    for (int o = 0; o < 4; ++o) lg[o] = fcb[o];
    for (int f = 0; f < 512; ++f) {
        float p = pooled[g * 512 + f] * inv;
#pragma unroll
        for (int o = 0; o < 4; ++o) lg[o] = fmaf(p, fcw[f * 4 + o], lg[o]);
    }
    float m = fmaxf(fmaxf(lg[0], lg[1]), fmaxf(lg[2], lg[3]));
    float s = 0.f;
#pragma unroll
    for (int o = 0; o < 4; ++o) s += expf(lg[o] - m);
    float l = logf(s);
#pragma unroll
    for (int o = 0; o < 4; ++o) out[g * 4 + o] = lg[o] - m - l;
}

// -------------------- launch --------------------

extern "C" void kernel_launch(void* const* d_in, const int* in_sizes, int n_in,
                              void* d_out, int out_size, void* d_ws, size_t ws_size,
                              hipStream_t stream) {
    const float* x   = (const float*)d_in[0];
    const int* ei    = (const int*)d_in[1];
    const int* batch = (const int*)d_in[2];
    const float* W11 = (const float*)d_in[3];
    const float* b11 = (const float*)d_in[4];
    const float* W12 = (const float*)d_in[5];
    const float* b12 = (const float*)d_in[6];
    const float* W21 = (const float*)d_in[7];
    const float* b21 = (const float*)d_in[8];
    const float* W22 = (const float*)d_in[9];
    const float* b22 = (const float*)d_in[10];
    const float* fcw = (const float*)d_in[11];
    const float* fcb = (const float*)d_in[12];
    float* out = (float*)d_out;

    const int N = in_sizes[0] / F1;
    const int E = in_sizes[1] / 2;
    const int* src = ei;
    const int* dst = ei + E;

    char* w = (char*)d_ws;
    size_t pos = 0;
    auto alloc = [&](size_t bytes) -> void* {
        void* p = w + pos;
        pos += (bytes + 255) & ~(size_t)255;
        return p;
    };
    int* cur_f   = (int*)alloc((size_t)N * 4);
    int* cur_r   = (int*)alloc((size_t)N * 4);
    int* off_f   = (int*)alloc((size_t)(N + 1) * 4);
    int* off_r   = (int*)alloc((size_t)(N + 1) * 4);
    float* dinvF = (float*)alloc((size_t)N * 4);
    float* dinvR = (float*)alloc((size_t)N * 4);
    int2* ed_f   = (int2*)alloc((size_t)E * 8);
    int2* ed_r   = (int2*)alloc((size_t)E * 8);
    int* blks_f  = (int*)alloc(1024);
    int* blks_r  = (int*)alloc(1024);
    int* gstart  = (int*)alloc((NGRAPH + 1) * 4);
    float* pooled = (float*)alloc((size_t)NGRAPH * 512 * 4);
    ushort_t* BpF = (ushort_t*)alloc((size_t)FT2 * O2 * 2);      // 320 KB packed W21
    ushort_t* BpR = (ushort_t*)alloc((size_t)FT2 * O2 * 2);      // 320 KB packed W22
    ushort_t* Bp1F = (ushort_t*)alloc((size_t)4 * KS1 * 64 * 8 * 2);  // 12 KB packed W11
    ushort_t* Bp1R = (ushort_t*)alloc((size_t)4 * KS1 * 64 * 8 * 2);  // 12 KB packed W12
    float* TxAll1 = (float*)alloc(((size_t)N * FT1 + 256) * 4);  // 32 MB fp32 + k-pad
    ushort_t* TxAll2 = (ushort_t*)alloc((size_t)(N + 64) * FT2 * 2);  // 128 MB bf16 + pad
    // total ~173.5 MB

    (void)hipMemsetAsync(cur_f, 0, (size_t)N * 4, stream);
    (void)hipMemsetAsync(cur_r, 0, (size_t)N * 4, stream);
    (void)hipMemsetAsync(pooled, 0, (size_t)NGRAPH * 512 * 4, stream);

    int gE = (E + 255) / 256, gN = (N + 255) / 256;
    k_count<<<gE, 256, 0, stream>>>(src, dst, cur_f, cur_r, E);
    k_dinv<<<gN, 256, 0, stream>>>(cur_f, cur_r, dinvF, dinvR, N);

    int NB = (N + 511) / 512;
    k_scan1<<<NB, 256, 0, stream>>>(cur_f, off_f, blks_f, N);
    k_scan1<<<NB, 256, 0, stream>>>(cur_r, off_r, blks_r, N);
    k_scan2<<<1, 256, 0, stream>>>(blks_f, NB);
    k_scan2<<<1, 256, 0, stream>>>(blks_r, NB);
    k_scan3<<<NB, 256, 0, stream>>>(off_f, blks_f, N);
    k_scan3<<<NB, 256, 0, stream>>>(off_r, blks_r, N);
    k_tail<<<1, 64, 0, stream>>>(off_f, off_r, N, E);
    (void)hipMemcpyAsync(cur_f, off_f, (size_t)N * 4, hipMemcpyDeviceToDevice, stream);
    (void)hipMemcpyAsync(cur_r, off_r, (size_t)N * 4, hipMemcpyDeviceToDevice, stream);
    k_scatter<<<gE, 256, 0, stream>>>(src, dst, dinvF, dinvR, cur_f, cur_r,
                                      ed_f, ed_r, E);
    k_gstart<<<5, 64, 0, stream>>>(batch, gstart, N);
    k_packW<<<80, 256, 0, stream>>>(W21, BpF);
    k_packW<<<80, 256, 0, stream>>>(W22, BpR);
    k_packW1<<<3, 256, 0, stream>>>(W11, Bp1F);
    k_packW1<<<3, 256, 0, stream>>>(W12, Bp1R);

    // ---------------- layer 1 (fp32 Tx, F=16) ----------------
    k_copyx<<<(N * 4 + 255) / 256, 256, 0, stream>>>(x, TxAll1, N);
    int gs1 = (N * 4 + 255) / 256;
    int gg1 = (N + 63) / 64;
    auto C1 = [&](int k) { return TxAll1 + k * F1; };
    // fwd
    k_spmm_f32<<<gs1, 256, 0, stream>>>(C1(0), C1(1), nullptr, off_f, ed_f, N);
    k_spmm_f32<<<gs1, 256, 0, stream>>>(C1(1), C1(2), C1(0), off_f, ed_f, N);
    k_spmm_f32<<<gs1, 256, 0, stream>>>(C1(2), C1(3), C1(1), off_f, ed_f, N);
    k_spmm_f32<<<gs1, 256, 0, stream>>>(C1(3), C1(4), C1(2), off_f, ed_f, N);
    k_gemm1_mfma<<<gg1, 256, 0, stream>>>(TxAll1, Bp1F, b11, TxAll2, N);
    // rev (overwrites C1(1..4); C1(0)=x preserved)
    k_spmm_f32<<<gs1, 256, 0, stream>>>(C1(0), C1(1), nullptr, off_r, ed_r, N);
    k_spmm_f32<<<gs1, 256, 0, stream>>>(C1(1), C1(2), C1(0), off_r, ed_r, N);
    k_spmm_f32<<<gs1, 256, 0, stream>>>(C1(2), C1(3), C1(1), off_r, ed_r, N);
    k_spmm_f32<<<gs1, 256, 0, stream>>>(C1(3), C1(4), C1(2), off_r, ed_r, N);
    k_gemm1_mfma<<<gg1, 256, 0, stream>>>(TxAll1, Bp1R, b12, TxAll2 + O1, N);

    // ---------------- layer 2 (bf16 Tx, F=128) ----------------
    int gs2 = (N + 3) / 4;
    auto C2 = [&](int k) { return TxAll2 + k * F2; };
    int gg = (N + 63) / 64;
    // fwd
    k_spmm_bf<<<gs2, 256, 0, stream>>>(C2(0), C2(1), nullptr, off_f, ed_f, N);
    k_spmm_bf<<<gs2, 256, 0, stream>>>(C2(1), C2(2), C2(0), off_f, ed_f, N);
    k_spmm_bf<<<gs2, 256, 0, stream>>>(C2(2), C2(3), C2(1), off_f, ed_f, N);
    k_spmm_bf<<<gs2, 256, 0, stream>>>(C2(3), C2(4), C2(2), off_f, ed_f, N);
    k_gemm2_mfma<<<gg, 256, 0, stream>>>(TxAll2, BpF, b21, pooled, 0, batch, N);
    // rev
    k_spmm_bf<<<gs2, 256, 0, stream>>>(C2(0), C2(1), nullptr, off_r, ed_r, N);
    k_spmm_bf<<<gs2, 256, 0, stream>>>(C2(1), C2(2), C2(0), off_r, ed_r, N);
    k_spmm_bf<<<gs2, 256, 0, stream>>>(C2(2), C2(3), C2(1), off_r, ed_r, N);
    k_spmm_bf<<<gs2, 256, 0, stream>>>(C2(3), C2(4), C2(2), off_r, ed_r, N);
    k_gemm2_mfma<<<gg, 256, 0, stream>>>(TxAll2, BpR, b22, pooled, 256, batch, N);

    k_logits<<<1, 256, 0, stream>>>(pooled, gstart, fcw, fcb, out);
}

// Round 16
// 750.156 us; speedup vs baseline: 1.0421x; 1.0161x over previous
//
#include <hip/hip_runtime.h>
#include <stdint.h>

#define NNODES 100000
#define NEDGES 600000
#define NGRAPH 256
#define KCH 5
#define F1 16
#define O1 64
#define F2 128
#define O2 256
#define FT1 (KCH * F1) /* 80  */
#define FT2 (KCH * F2) /* 640 */
#define KSTEPS 20      /* 640/32 */
#define KS1 3          /* ceil(80/32) for layer-1 MFMA GEMM (K padded to 96) */
#define LROW 40        /* LDS row stride in ushorts: 80 B -> 16B-aligned rows */

typedef unsigned short ushort_t;
typedef __attribute__((ext_vector_type(8))) short bf16x8;
typedef __attribute__((ext_vector_type(4))) float f32x4;

__device__ __forceinline__ float bflo(unsigned int u) {
    union { unsigned int u; float f; } v; v.u = u << 16; return v.f;
}
__device__ __forceinline__ float bfhi(unsigned int u) {
    union { unsigned int u; float f; } v; v.u = u & 0xFFFF0000u; return v.f;
}
__device__ __forceinline__ unsigned int f2bf(float f) {
    union { float f; unsigned int u; } v; v.f = f;
    return (v.u + 0x7FFFu + ((v.u >> 16) & 1u)) >> 16;  // RNE
}
__device__ __forceinline__ unsigned int pack2(float lo, float hi) {
    return (f2bf(hi) << 16) | f2bf(lo);
}

// -------------------- CSR build --------------------

__global__ void k_count(const int* __restrict__ src, const int* __restrict__ dst,
                        int* __restrict__ cntDst, int* __restrict__ cntSrc, int E) {
    int e = blockIdx.x * 256 + threadIdx.x;
    if (e < E) {
        atomicAdd(&cntDst[dst[e]], 1);
        atomicAdd(&cntSrc[src[e]], 1);
    }
}

__global__ void k_dinv(const int* __restrict__ cntDst, const int* __restrict__ cntSrc,
                       float* __restrict__ dinvF, float* __restrict__ dinvR, int n) {
    int i = blockIdx.x * 256 + threadIdx.x;
    if (i < n) {
        int cs = cntSrc[i], cd = cntDst[i];
        dinvF[i] = cs > 0 ? rsqrtf((float)cs) : 0.f;  // deg over src -> fwd norm
        dinvR[i] = cd > 0 ? rsqrtf((float)cd) : 0.f;  // deg over dst -> rev norm
    }
}

// exclusive scan, 512 elems/block
__global__ void k_scan1(const int* __restrict__ in, int* __restrict__ out,
                        int* __restrict__ blksum, int n) {
    __shared__ int a[512];
    __shared__ int s[256];
    int t = threadIdx.x;
    int base = blockIdx.x * 512;
    a[t]       = (base + t < n)       ? in[base + t]       : 0;
    a[t + 256] = (base + t + 256 < n) ? in[base + t + 256] : 0;
    __syncthreads();
    s[t] = a[2 * t] + a[2 * t + 1];
    __syncthreads();
    for (int off = 1; off < 256; off <<= 1) {
        int v = (t >= off) ? s[t - off] : 0;
        __syncthreads();
        s[t] += v;
        __syncthreads();
    }
    int ep = (t > 0) ? s[t - 1] : 0;  // exclusive over pairs
    if (base + 2 * t < n)     out[base + 2 * t]     = ep;
    if (base + 2 * t + 1 < n) out[base + 2 * t + 1] = ep + a[2 * t];
    if (t == 255) blksum[blockIdx.x] = s[255];
}

__global__ void k_scan2(int* __restrict__ blksum, int nb) {
    __shared__ int s[256];
    int t = threadIdx.x;
    s[t] = (t < nb) ? blksum[t] : 0;
    __syncthreads();
    for (int off = 1; off < 256; off <<= 1) {
        int v = (t >= off) ? s[t - off] : 0;
        __syncthreads();
        s[t] += v;
        __syncthreads();
    }
    if (t < nb) blksum[t] = (t > 0) ? s[t - 1] : 0;
}

__global__ void k_scan3(int* __restrict__ out, const int* __restrict__ blksum, int n) {
    int i = blockIdx.x * 512 + threadIdx.x;
    int add = blksum[blockIdx.x];
    if (i < n) out[i] += add;
    if (i + 256 < n) out[i + 256] += add;
}

__global__ void k_tail(int* __restrict__ off_f, int* __restrict__ off_r, int n, int E) {
    if (threadIdx.x == 0) { off_f[n] = E; off_r[n] = E; }
}

// edge record = {nbr, weight} packed in one int2 -> single 8B random store
__global__ void k_scatter(const int* __restrict__ src, const int* __restrict__ dst,
                          const float* __restrict__ dinvF, const float* __restrict__ dinvR,
                          int* __restrict__ curF, int* __restrict__ curR,
                          int2* __restrict__ edF, int2* __restrict__ edR, int E) {
    int e = blockIdx.x * 256 + threadIdx.x;
    if (e < E) {
        int s = src[e], d = dst[e];
        int p = atomicAdd(&curF[d], 1);
        float wf = -dinvF[s] * dinvF[d];
        edF[p] = make_int2(s, __float_as_int(wf));
        int q = atomicAdd(&curR[s], 1);
        float wr = -dinvR[s] * dinvR[d];
        edR[q] = make_int2(d, __float_as_int(wr));
    }
}

__global__ void k_gstart(const int* __restrict__ batch, int* __restrict__ gstart, int n) {
    int g = blockIdx.x * 64 + threadIdx.x;
    if (g > NGRAPH) return;
    if (g == NGRAPH) { gstart[g] = n; return; }
    int lo = 0, hi = n;
    while (lo < hi) {
        int mid = (lo + hi) >> 1;
        if (batch[mid] < g) lo = mid + 1; else hi = mid;
    }
    gstart[g] = lo;
}

// -------------------- compute --------------------

__global__ void k_copyx(const float* __restrict__ x, float* __restrict__ Tx, int n) {
    int tid = blockIdx.x * 256 + threadIdx.x;
    int r = tid >> 2, c = tid & 3;
    if (r < n)
        *(float4*)(Tx + (size_t)r * FT1 + c * 4) =
            *(const float4*)(x + (size_t)r * 16 + c * 4);
}

// fp32 SpMM (layer 1, F=16): 4 lanes/row, float4/lane; edge loop unrolled x4
__global__ void k_spmm_f32(const float* __restrict__ Hin, float* __restrict__ Hout,
                           const float* __restrict__ Tx0,
                           const int* __restrict__ off, const int2* __restrict__ ed,
                           int n) {
    int tid = blockIdx.x * 256 + threadIdx.x;
    int r = tid >> 2, c = tid & 3;
    if (r >= n) return;
    int j0 = off[r], j1 = off[r + 1];
    float4 s = {0.f, 0.f, 0.f, 0.f};
    int j = j0;
    for (; j + 4 <= j1; j += 4) {
        int2 e0 = ed[j], e1 = ed[j + 1], e2 = ed[j + 2], e3 = ed[j + 3];
        float wa = __int_as_float(e0.y), wb = __int_as_float(e1.y);
        float wc = __int_as_float(e2.y), wd = __int_as_float(e3.y);
        const float4 h0 = *(const float4*)(Hin + (size_t)e0.x * FT1 + c * 4);
        const float4 h1 = *(const float4*)(Hin + (size_t)e1.x * FT1 + c * 4);
        const float4 h2 = *(const float4*)(Hin + (size_t)e2.x * FT1 + c * 4);
        const float4 h3 = *(const float4*)(Hin + (size_t)e3.x * FT1 + c * 4);
        s.x += wa * h0.x; s.y += wa * h0.y; s.z += wa * h0.z; s.w += wa * h0.w;
        s.x += wb * h1.x; s.y += wb * h1.y; s.z += wb * h1.z; s.w += wb * h1.w;
        s.x += wc * h2.x; s.y += wc * h2.y; s.z += wc * h2.z; s.w += wc * h2.w;
        s.x += wd * h3.x; s.y += wd * h3.y; s.z += wd * h3.z; s.w += wd * h3.w;
    }
    for (; j < j1; ++j) {
        int2 e = ed[j];
        float w2 = __int_as_float(e.y);
        const float4 h = *(const float4*)(Hin + (size_t)e.x * FT1 + c * 4);
        s.x += w2 * h.x; s.y += w2 * h.y; s.z += w2 * h.z; s.w += w2 * h.w;
    }
    float4 o;
    if (Tx0) {
        const float4 t0 = *(const float4*)(Tx0 + (size_t)r * FT1 + c * 4);
        o.x = 2.f * s.x - t0.x; o.y = 2.f * s.y - t0.y;
        o.z = 2.f * s.z - t0.z; o.w = 2.f * s.w - t0.w;
    } else {
        o = s;
    }
    *(float4*)(Hout + (size_t)r * FT1 + c * 4) = o;
}

// bf16 SpMM (layer 2, F=128): one wave per row, scalar edge stream; clamped
// 8-slot edge block -> all gathers of a row issued back-to-back.
__global__ void k_spmm_bf(const ushort_t* __restrict__ Hin, ushort_t* __restrict__ Hout,
                          const ushort_t* __restrict__ Tx0,
                          const int* __restrict__ off, const int2* __restrict__ ed,
                          int n) {
    int r = blockIdx.x * 4 + (threadIdx.x >> 6);
    r = __builtin_amdgcn_readfirstlane(r);   // wave-uniform -> scalar edge loads
    int c = threadIdx.x & 63;
    if (r >= n) return;
    int j0 = __builtin_amdgcn_readfirstlane(off[r]);
    int j1 = __builtin_amdgcn_readfirstlane(off[r + 1]);
    float s0 = 0.f, s1 = 0.f;
    for (int j = j0; j < j1; j += 8) {
        float w[8];
        unsigned int h[8];
#pragma unroll
        for (int sl = 0; sl < 8; ++sl) {
            int jj = j + sl;
            int jc = jj < j1 ? jj : j1 - 1;
            int2 e = ed[jc];
            w[sl] = (jj < j1) ? __int_as_float(e.y) : 0.f;
            h[sl] = *(const unsigned int*)(Hin + (size_t)e.x * FT2 + c * 2);
        }
#pragma unroll
        for (int sl = 0; sl < 8; ++sl) {
            s0 = fmaf(bflo(h[sl]), w[sl], s0);
            s1 = fmaf(bfhi(h[sl]), w[sl], s1);
        }
    }
    if (Tx0) {
        unsigned int t0 = *(const unsigned int*)(Tx0 + (size_t)r * FT2 + c * 2);
        s0 = 2.f * s0 - bflo(t0);
        s1 = 2.f * s1 - bfhi(t0);
    }
    *(unsigned int*)(Hout + (size_t)r * FT2 + c * 2) = pack2(s0, s1);
}

// pack W [80,64] fp32 -> bf16 MFMA B-frags, K zero-padded 80 -> 96 (KS1 ksteps)
__global__ void k_packW1(const float* __restrict__ W, ushort_t* __restrict__ Bp) {
    int tid = blockIdx.x * 256 + threadIdx.x;  // 4*KS1*64 = 768 threads
    if (tid >= 4 * KS1 * 64) return;
    int lane = tid & 63;
    int ks = (tid >> 6) % KS1;
    int nt = tid / (64 * KS1);
    int k0 = ks * 32 + (lane >> 4) * 8;
    int ncol = nt * 16 + (lane & 15);
    float v[8];
#pragma unroll
    for (int j = 0; j < 8; ++j) {
        int k = k0 + j;
        v[j] = (k < FT1) ? W[(size_t)k * O1 + ncol] : 0.f;
    }
    uint4 o;
    o.x = pack2(v[0], v[1]); o.y = pack2(v[2], v[3]);
    o.z = pack2(v[4], v[5]); o.w = pack2(v[6], v[7]);
    *(uint4*)(Bp + (size_t)tid * 8) = o;
}

// layer-1 MFMA GEMM: A fp32 [n,80] (k-padded reads to 96) x Bp bf16 -> bf16 out
// slice (ld=640), bias+relu. Block = 4 waves; wave w: rows blk*64+w*16..+16.
__global__ __launch_bounds__(256) void k_gemm1_mfma(
    const float* __restrict__ A, const ushort_t* __restrict__ Bp,
    const float* __restrict__ bias, ushort_t* __restrict__ out, int n) {
    int lane = threadIdx.x & 63;
    int wvi = threadIdx.x >> 6;
    int mrow = lane & 15;
    int quad = lane >> 4;
    int m0w = blockIdx.x * 64 + wvi * 16;
    int row = m0w + mrow;
    int rowc = row < n ? row : n - 1;  // clamp loads; stores masked below
    const float* Ar = A + (size_t)rowc * FT1 + quad * 8;

    f32x4 acc[4] = {};
#pragma unroll
    for (int ks = 0; ks < KS1; ++ks) {
        float4 a0 = *(const float4*)(Ar + ks * 32);
        float4 a1 = *(const float4*)(Ar + ks * 32 + 4);
        union { bf16x8 v; unsigned int u[4]; } ua;
        ua.u[0] = pack2(a0.x, a0.y);
        ua.u[1] = pack2(a0.z, a0.w);
        ua.u[2] = pack2(a1.x, a1.y);
        ua.u[3] = pack2(a1.z, a1.w);
#pragma unroll
        for (int nf = 0; nf < 4; ++nf) {
            bf16x8 bfr = *(const bf16x8*)(Bp + ((size_t)(nf * KS1 + ks) * 64 + lane) * 8);
            acc[nf] = __builtin_amdgcn_mfma_f32_16x16x32_bf16(ua.v, bfr, acc[nf], 0, 0, 0);
        }
    }
    // C/D layout: col = nf*16 + (lane&15), row = m0w + quad*4 + reg
#pragma unroll
    for (int nf = 0; nf < 4; ++nf) {
        float bb = bias[nf * 16 + mrow];
#pragma unroll
        for (int reg = 0; reg < 4; ++reg) {
            int orow = m0w + quad * 4 + reg;
            if (orow < n)
                out[(size_t)orow * FT2 + nf * 16 + mrow] =
                    (ushort_t)f2bf(fmaxf(acc[nf][reg] + bb, 0.f));
        }
    }
}

// pack W [640,256] fp32 row-major -> bf16 MFMA B-fragment layout
__global__ void k_packW(const float* __restrict__ W, ushort_t* __restrict__ Bp) {
    int tid = blockIdx.x * 256 + threadIdx.x;  // 16*KSTEPS*64 = 20480 threads
    if (tid >= 16 * KSTEPS * 64) return;
    int lane = tid & 63;
    int ks = (tid >> 6) % KSTEPS;
    int nt = tid / (64 * KSTEPS);
    int k0 = ks * 32 + (lane >> 4) * 8;
    int ncol = nt * 16 + (lane & 15);
    float v[8];
#pragma unroll
    for (int j = 0; j < 8; ++j) v[j] = W[(size_t)(k0 + j) * O2 + ncol];
    uint4 o;
    o.x = pack2(v[0], v[1]); o.y = pack2(v[2], v[3]);
    o.z = pack2(v[4], v[5]); o.w = pack2(v[6], v[7]);
    *(uint4*)(Bp + (size_t)tid * 8) = o;
}

// layer-2 MFMA GEMM, double-buffered LDS A + register double-buffered B:
// both operands for stage ks+1 are in flight while stage ks computes.
__global__ __launch_bounds__(256) void k_gemm2_mfma(
    const ushort_t* __restrict__ A, const ushort_t* __restrict__ Bp,
    const float* __restrict__ bias, float* __restrict__ pooled, int colofs,
    const int* __restrict__ batch, int n) {
    __shared__ ushort_t lds[2][64 * LROW];  // 2 x 5120 B

    int lane = threadIdx.x & 63;
    int wv = threadIdx.x >> 6;
    int m0 = blockIdx.x * 64;
    int mrow = lane & 15;
    int quad = lane >> 4;
    int srow = threadIdx.x >> 2;  // staging row 0..63
    int sc = threadIdx.x & 3;     // staging 16B chunk 0..3

    const ushort_t* Ag = A + (size_t)(m0 + srow) * FT2 + sc * 8;
    const ushort_t* Bbase = Bp + ((size_t)(wv * 4) * KSTEPS * 64 + lane) * 8;
    int sidx = srow * LROW + sc * 8;

    f32x4 acc[4][4] = {};  // [mfrag][nfrag]

    // prologue: A stage 0 -> buf0; A stage 1 in regs; B stage 0 in regs
    uint4 nxt;
    bf16x8 bcur[4], bnxt[4];
    {
        uint4 c0 = *(const uint4*)(Ag);
        *(uint4*)&lds[0][sidx] = c0;
        nxt = *(const uint4*)(Ag + 32);
#pragma unroll
        for (int nf = 0; nf < 4; ++nf)
            bcur[nf] = *(const bf16x8*)(Bbase + ((size_t)nf * KSTEPS) * 64 * 8);
    }

    for (int ks = 0; ks < KSTEPS; ++ks) {
        __syncthreads();
        // write A stage ks+1 (loaded one iteration ago) into the other buffer
        if (ks + 1 < KSTEPS)
            *(uint4*)&lds[(ks + 1) & 1][sidx] = nxt;
        // issue A load for stage ks+2 (consumed next iteration)
        if (ks + 2 < KSTEPS)
            nxt = *(const uint4*)(Ag + (ks + 2) * 32);
        // issue B load for stage ks+1 (consumed next iteration)
        if (ks + 1 < KSTEPS) {
#pragma unroll
            for (int nf = 0; nf < 4; ++nf)
                bnxt[nf] = *(const bf16x8*)(Bbase + ((size_t)nf * KSTEPS + ks + 1) * 64 * 8);
        }
        bf16x8 af[4];
        const ushort_t* lbuf = &lds[ks & 1][0];
#pragma unroll
        for (int mf = 0; mf < 4; ++mf)
            af[mf] = *(const bf16x8*)(lbuf + (mf * 16 + mrow) * LROW + quad * 8);
#pragma unroll
        for (int mf = 0; mf < 4; ++mf)
#pragma unroll
            for (int nf = 0; nf < 4; ++nf)
                acc[mf][nf] = __builtin_amdgcn_mfma_f32_16x16x32_bf16(
                    af[mf], bcur[nf], acc[mf][nf], 0, 0, 0);
#pragma unroll
        for (int nf = 0; nf < 4; ++nf) bcur[nf] = bnxt[nf];
    }

    // epilogue: C/D layout col=lane&15, row=quad*4+reg; pool into pooled[g*512+colofs+col]
    float bcol[4];
#pragma unroll
    for (int nf = 0; nf < 4; ++nf) bcol[nf] = bias[wv * 64 + nf * 16 + mrow];

#pragma unroll
    for (int mf = 0; mf < 4; ++mf) {
        int t0 = m0 + mf * 16;
        if (t0 >= n) break;
        int te = (t0 + 15 < n) ? t0 + 15 : n - 1;
        int r0 = t0 + quad * 4;
        if (batch[t0] == batch[te]) {
            // whole 16-row tile in one graph: cross-quad reduce, 1 atomic / (nf, col)
            int g = batch[t0];
#pragma unroll
            for (int nf = 0; nf < 4; ++nf) {
                float s = 0.f;
#pragma unroll
                for (int reg = 0; reg < 4; ++reg) {
                    float v = fmaxf(acc[mf][nf][reg] + bcol[nf], 0.f);
                    if (r0 + reg < n) s += v;
                }
                s += __shfl_xor(s, 16, 64);
                s += __shfl_xor(s, 32, 64);
                if (quad == 0)
                    atomicAdd(pooled + (size_t)g * 512 + colofs + wv * 64 + nf * 16 + mrow, s);
            }
        } else {
            // boundary tile: per-lane run merge over 4 consecutive rows
            int gb[4];
#pragma unroll
            for (int reg = 0; reg < 4; ++reg)
                gb[reg] = batch[(r0 + reg < n) ? r0 + reg : n - 1];
#pragma unroll
            for (int nf = 0; nf < 4; ++nf) {
                int col = colofs + wv * 64 + nf * 16 + mrow;
                float run = 0.f;
                int g = gb[0];
                bool any = false;
#pragma unroll
                for (int reg = 0; reg < 4; ++reg) {
                    int row = r0 + reg;
                    if (row >= n) break;
                    float v = fmaxf(acc[mf][nf][reg] + bcol[nf], 0.f);
                    if (gb[reg] != g) {
                        atomicAdd(pooled + (size_t)g * 512 + col, run);
                        run = 0.f;
                        g = gb[reg];
                    }
                    run += v;
                    any = true;
                }
                if (any) atomicAdd(pooled + (size_t)g * 512 + col, run);
            }
        }
    }
}

__global__ void k_logits(const float* __restrict__ pooled, const int* __restrict__ gstart,
                         const float* __restrict__ fcw, const float* __restrict__ fcb,
                         float* __restrict__ out) {
    int g = threadIdx.x;
    int cnt = gstart[g + 1] - gstart[g];
    float inv = 1.f / (float)(cnt > 1 ? cnt : 1);
    float lg[4];
#pragma unroll
    for (int o = 0; o < 4; ++o) lg[o] = fcb[o];
    for (int f = 0; f < 512; ++f) {
        float p = pooled[g * 512 + f] * inv;
#pragma unroll
        for (int o = 0; o < 4; ++o) lg[o] = fmaf(p, fcw[f * 4 + o], lg[o]);
    }
    float m = fmaxf(fmaxf(lg[0], lg[1]), fmaxf(lg[2], lg[3]));
    float s = 0.f;
#pragma unroll
    for (int o = 0; o < 4; ++o) s += expf(lg[o] - m);
    float l = logf(s);
#pragma unroll
    for (int o = 0; o < 4; ++o) out[g * 4 + o] = lg[o] - m - l;
}

// -------------------- launch --------------------

extern "C" void kernel_launch(void* const* d_in, const int* in_sizes, int n_in,
                              void* d_out, int out_size, void* d_ws, size_t ws_size,
                              hipStream_t stream) {
    const float* x   = (const float*)d_in[0];
    const int* ei    = (const int*)d_in[1];
    const int* batch = (const int*)d_in[2];
    const float* W11 = (const float*)d_in[3];
    const float* b11 = (const float*)d_in[4];
    const float* W12 = (const float*)d_in[5];
    const float* b12 = (const float*)d_in[6];
    const float* W21 = (const float*)d_in[7];
    const float* b21 = (const float*)d_in[8];
    const float* W22 = (const float*)d_in[9];
    const float* b22 = (const float*)d_in[10];
    const float* fcw = (const float*)d_in[11];
    const float* fcb = (const float*)d_in[12];
    float* out = (float*)d_out;

    const int N = in_sizes[0] / F1;
    const int E = in_sizes[1] / 2;
    const int* src = ei;
    const int* dst = ei + E;

    char* w = (char*)d_ws;
    size_t pos = 0;
    auto alloc = [&](size_t bytes) -> void* {
        void* p = w + pos;
        pos += (bytes + 255) & ~(size_t)255;
        return p;
    };
    int* cur_f   = (int*)alloc((size_t)N * 4);
    int* cur_r   = (int*)alloc((size_t)N * 4);
    int* off_f   = (int*)alloc((size_t)(N + 1) * 4);
    int* off_r   = (int*)alloc((size_t)(N + 1) * 4);
    float* dinvF = (float*)alloc((size_t)N * 4);
    float* dinvR = (float*)alloc((size_t)N * 4);
    int2* ed_f   = (int2*)alloc((size_t)E * 8);
    int2* ed_r   = (int2*)alloc((size_t)E * 8);
    int* blks_f  = (int*)alloc(1024);
    int* blks_r  = (int*)alloc(1024);
    int* gstart  = (int*)alloc((NGRAPH + 1) * 4);
    float* pooled = (float*)alloc((size_t)NGRAPH * 512 * 4);
    ushort_t* BpF = (ushort_t*)alloc((size_t)FT2 * O2 * 2);      // 320 KB packed W21
    ushort_t* BpR = (ushort_t*)alloc((size_t)FT2 * O2 * 2);      // 320 KB packed W22
    ushort_t* Bp1F = (ushort_t*)alloc((size_t)4 * KS1 * 64 * 8 * 2);  // 12 KB packed W11
    ushort_t* Bp1R = (ushort_t*)alloc((size_t)4 * KS1 * 64 * 8 * 2);  // 12 KB packed W12
    float* TxAll1 = (float*)alloc(((size_t)N * FT1 + 256) * 4);  // 32 MB fp32 + k-pad
    ushort_t* TxAll2 = (ushort_t*)alloc((size_t)(N + 64) * FT2 * 2);  // 128 MB bf16 + pad
    // total ~173.5 MB

    (void)hipMemsetAsync(cur_f, 0, (size_t)N * 4, stream);
    (void)hipMemsetAsync(cur_r, 0, (size_t)N * 4, stream);
    (void)hipMemsetAsync(pooled, 0, (size_t)NGRAPH * 512 * 4, stream);

    int gE = (E + 255) / 256, gN = (N + 255) / 256;
    k_count<<<gE, 256, 0, stream>>>(src, dst, cur_f, cur_r, E);
    k_dinv<<<gN, 256, 0, stream>>>(cur_f, cur_r, dinvF, dinvR, N);

    int NB = (N + 511) / 512;
    k_scan1<<<NB, 256, 0, stream>>>(cur_f, off_f, blks_f, N);
    k_scan1<<<NB, 256, 0, stream>>>(cur_r, off_r, blks_r, N);
    k_scan2<<<1, 256, 0, stream>>>(blks_f, NB);
    k_scan2<<<1, 256, 0, stream>>>(blks_r, NB);
    k_scan3<<<NB, 256, 0, stream>>>(off_f, blks_f, N);
    k_scan3<<<NB, 256, 0, stream>>>(off_r, blks_r, N);
    k_tail<<<1, 64, 0, stream>>>(off_f, off_r, N, E);
    (void)hipMemcpyAsync(cur_f, off_f, (size_t)N * 4, hipMemcpyDeviceToDevice, stream);
    (void)hipMemcpyAsync(cur_r, off_r, (size_t)N * 4, hipMemcpyDeviceToDevice, stream);
    k_scatter<<<gE, 256, 0, stream>>>(src, dst, dinvF, dinvR, cur_f, cur_r,
                                      ed_f, ed_r, E);
    k_gstart<<<5, 64, 0, stream>>>(batch, gstart, N);
    k_packW<<<80, 256, 0, stream>>>(W21, BpF);
    k_packW<<<80, 256, 0, stream>>>(W22, BpR);
    k_packW1<<<3, 256, 0, stream>>>(W11, Bp1F);
    k_packW1<<<3, 256, 0, stream>>>(W12, Bp1R);

    // ---------------- layer 1 (fp32 Tx, F=16) ----------------
    k_copyx<<<(N * 4 + 255) / 256, 256, 0, stream>>>(x, TxAll1, N);
    int gs1 = (N * 4 + 255) / 256;
    int gg1 = (N + 63) / 64;
    auto C1 = [&](int k) { return TxAll1 + k * F1; };
    // fwd
    k_spmm_f32<<<gs1, 256, 0, stream>>>(C1(0), C1(1), nullptr, off_f, ed_f, N);
    k_spmm_f32<<<gs1, 256, 0, stream>>>(C1(1), C1(2), C1(0), off_f, ed_f, N);
    k_spmm_f32<<<gs1, 256, 0, stream>>>(C1(2), C1(3), C1(1), off_f, ed_f, N);
    k_spmm_f32<<<gs1, 256, 0, stream>>>(C1(3), C1(4), C1(2), off_f, ed_f, N);
    k_gemm1_mfma<<<gg1, 256, 0, stream>>>(TxAll1, Bp1F, b11, TxAll2, N);
    // rev (overwrites C1(1..4); C1(0)=x preserved)
    k_spmm_f32<<<gs1, 256, 0, stream>>>(C1(0), C1(1), nullptr, off_r, ed_r, N);
    k_spmm_f32<<<gs1, 256, 0, stream>>>(C1(1), C1(2), C1(0), off_r, ed_r, N);
    k_spmm_f32<<<gs1, 256, 0, stream>>>(C1(2), C1(3), C1(1), off_r, ed_r, N);
    k_spmm_f32<<<gs1, 256, 0, stream>>>(C1(3), C1(4), C1(2), off_r, ed_r, N);
    k_gemm1_mfma<<<gg1, 256, 0, stream>>>(TxAll1, Bp1R, b12, TxAll2 + O1, N);

    // ---------------- layer 2 (bf16 Tx, F=128) ----------------
    int gs2 = (N + 3) / 4;
    auto C2 = [&](int k) { return TxAll2 + k * F2; };
    int gg = (N + 63) / 64;
    // fwd
    k_spmm_bf<<<gs2, 256, 0, stream>>>(C2(0), C2(1), nullptr, off_f, ed_f, N);
    k_spmm_bf<<<gs2, 256, 0, stream>>>(C2(1), C2(2), C2(0), off_f, ed_f, N);
    k_spmm_bf<<<gs2, 256, 0, stream>>>(C2(2), C2(3), C2(1), off_f, ed_f, N);
    k_spmm_bf<<<gs2, 256, 0, stream>>>(C2(3), C2(4), C2(2), off_f, ed_f, N);
    k_gemm2_mfma<<<gg, 256, 0, stream>>>(TxAll2, BpF, b21, pooled, 0, batch, N);
    // rev
    k_spmm_bf<<<gs2, 256, 0, stream>>>(C2(0), C2(1), nullptr, off_r, ed_r, N);
    k_spmm_bf<<<gs2, 256, 0, stream>>>(C2(1), C2(2), C2(0), off_r, ed_r, N);
    k_spmm_bf<<<gs2, 256, 0, stream>>>(C2(2), C2(3), C2(1), off_r, ed_r, N);
    k_spmm_bf<<<gs2, 256, 0, stream>>>(C2(3), C2(4), C2(2), off_r, ed_r, N);
    k_gemm2_mfma<<<gg, 256, 0, stream>>>(TxAll2, BpR, b22, pooled, 256, batch, N);

    k_logits<<<1, 256, 0, stream>>>(pooled, gstart, fcw, fcb, out);
}